// Round 4
// baseline (95.376 us; speedup 1.0000x reference)
//
#include <hip/hip_runtime.h>
#include <math.h>

// Problem constants (fixed by setup_inputs in the reference)
#define N_  4
#define A_  3
#define S_  13
#define NC_ 80
#define NM_ 32
#define G_  16
#define H_  104
#define W_  104
#define CH_ (5 + NC_ + NM_)   // 117
#define HW_ (H_ * W_)
#define NCELL (N_ * A_ * S_ * S_)  // 2028

#define MAIN_BLOCKS 256
#define P1_BLOCKS 8
#define P2_BLOCKS (MAIN_BLOCKS - P1_BLOCKS)   // 248
#define P2_WAVES  (P2_BLOCKS * 4)             // 992 phase-2 waves
#define P2_K 3      // candidates per wave: ceil(2028/992) = 3 (lanes 0..2)
#define PROW 16     // floats per partial row (16*4 = 64B; rows padded)

// d_ws layout: partials[MAIN_BLOCKS][PROW] floats, then one u32 ticket.
// slots 0..7 (valid only rows 0..7): n_obj, n_noobj, noobj_bce, obj_bce,
//                                    xy_bce, wh_mse, one_minus_giou, nll
// slots 8..9 (all rows): seg_sum, n_valid  (rows 0..7 write zeros)
// All written UNCONDITIONALLY by their owning block -> no memset needed.
//
// Ticket correctness under 0xAA poison: atomicInc(ticket, 255) stores
// (old >= 255 ? 0 : old+1). Start state is either 0xAAAAAAAA (poison) or 255
// (our leftover); both >= 255 -> arrival 1 wraps to 0, arrivals 2..256
// observe old = 0..254. The 256th arriver ALWAYS observes old == 254 and
// runs finalize; end state is always 255.
//
// Fence discipline (R1 lesson, R3-validated): __syncthreads() drains the
// block's stores to L2, then ONE tid-0 __threadfence() (release) before the
// ticket bump, and ONE acquire fence in the reading wave of the last block.
// Per-thread fences in all blocks cost µs (R1: +3.2 µs).

__device__ __forceinline__ float bce_logits(float x, float z) {
    return fmaxf(x, 0.0f) - x * z + log1pf(expf(-fabsf(x)));
}

__device__ __forceinline__ float sigmoidf(float x) {
    return 1.0f / (1.0f + expf(-x));
}

__device__ __forceinline__ float readlane_f(float v, int l) {
    return __int_as_float(__builtin_amdgcn_readlane(__float_as_int(v), l));
}

__device__ __forceinline__ float giou_fn(float cx1, float cy1, float w1, float h1,
                                         float cx2, float cy2, float w2, float h2) {
    const float eps = 1e-9f;
    float b1x1 = cx1 - w1 * 0.5f, b1y1 = cy1 - h1 * 0.5f;
    float b1x2 = cx1 + w1 * 0.5f, b1y2 = cy1 + h1 * 0.5f;
    float b2x1 = cx2 - w2 * 0.5f, b2y1 = cy2 - h2 * 0.5f;
    float b2x2 = cx2 + w2 * 0.5f, b2y2 = cy2 + h2 * 0.5f;
    float a1 = fmaxf(b1x2 - b1x1, 0.0f) * fmaxf(b1y2 - b1y1, 0.0f) + eps;
    float a2 = fmaxf(b2x2 - b2x1, 0.0f) * fmaxf(b2y2 - b2y1, 0.0f) + eps;
    float iw = fmaxf(fminf(b1x2, b2x2) - fmaxf(b1x1, b2x1), 0.0f);
    float ih = fmaxf(fminf(b1y2, b2y2) - fmaxf(b1y1, b2y1), 0.0f);
    float inter = iw * ih + eps;
    float uni   = a1 + a2 - inter + eps;
    float iou   = inter / uni;
    float cw = fmaxf(b1x2, b2x2) - fminf(b1x1, b2x1);
    float ch = fmaxf(b1y2, b2y2) - fminf(b1y1, b2y1);
    float carea = cw * ch + eps;
    return iou - (carea - uni) / carea;
}

// box pixel bounds for a cell (value form)
__device__ __forceinline__ void region_bounds_v(float t0, float t1, float t2, float t3,
                                                int i, int j,
                                                int& lox, int& loy, int& ncols, int& nrows) {
    float bx = (t0 + (float)j) * ((float)W_ / (float)S_);
    float by = (t1 + (float)i) * ((float)H_ / (float)S_);
    float bw = t2 * ((float)W_ / (float)S_);
    float bh = t3 * ((float)H_ / (float)S_);
    int x1 = (int)floorf(bx - bw * 0.5f);
    int x2 = (int)floorf(bx + bw * 0.5f);
    int y1 = (int)floorf(by - bh * 0.5f);
    int y2 = (int)floorf(by + bh * 0.5f);
    lox = max(x1, 0); loy = max(y1, 0);
    ncols = max(min(x2, W_) - lox, 0);
    nrows = max(min(y2, H_) - loy, 0);
}

// ---------------------------------------------------------------------------
// SINGLE fused kernel, 256 blocks x 256 threads (1 block/CU):
//  Blocks 0..7   : phase 1 — thread-per-cell scalar losses -> partial rows.
//  Blocks 8..255 : phase 2 — seg BCE, 992 global waves, 3 candidates each.
//    Round 1 (all loads issue together, all HBM-cold):
//      lanes 0..2   : full t-row of candidate c_l = gw + l*992 -> bounds.
//      lanes 0..63  : tanh(coeff) of cand 0/1 (halves), cand 2 on lanes 0..31
//                     -- coeff addresses are STATIC, independent of probe.
//    ballot -> per valid cell: bounds/id/coeffs all via readlane (register
//    only); ONLY the proto/mask gather round remains. Serial depth ~1 cell.
//  Epilogue: per-block single-thread release fence + ticket; 256th arriver
//    acquires and reduces all partial rows, writes the 6 outputs.
// ---------------------------------------------------------------------------
__global__ __launch_bounds__(256) void yolo_fused_kernel(
    const float* __restrict__ preds,    // (N,A,S,S,117)
    const float* __restrict__ target,   // (N,A,S,S,7)
    const float* __restrict__ anchors,  // (A,2)
    const float* __restrict__ protos,   // (N,32,H,W)
    const float* __restrict__ masks,    // (N,16,H,W)
    float* __restrict__ partials,
    unsigned int* __restrict__ ticket,
    float* __restrict__ out)
{
    const int b    = blockIdx.x;
    const int tid  = threadIdx.x;
    const int wav  = tid >> 6;
    const int lane = tid & 63;

    __shared__ float s_w[4][8];     // phase-1 cross-wave
    __shared__ float s_seg[4];      // phase-2 cross-wave
    __shared__ int   s_nv[4];
    __shared__ int   s_last;

    if (b < P1_BLOCKS) {
        // ===================== Phase 1: scalar losses ======================
        const int cell = b * 256 + tid;
        float v0 = 0.f, v1 = 0.f, v2 = 0.f, v3 = 0.f,
              v4 = 0.f, v5 = 0.f, v6 = 0.f, v7 = 0.f;

        if (cell < NCELL) {
            const int a = (cell / (S_ * S_)) % A_;
            const float* t = target + (size_t)cell * 7;
            const float* p = preds  + (size_t)cell * CH_;
            // hoist ALL round-1 loads before the branch (issue concurrently)
            float tx = t[0], ty = t[1], tw = t[2], th = t[3];
            float conf_t = t[4];
            float t5 = t[5];
            float p0 = p[0], p1 = p[1], p2 = p[2], p3 = p[3];
            float x  = p[4];

            if (conf_t == 0.0f) {
                v1 = 1.0f;
                v2 = bce_logits(x, 0.0f);
            } else if (conf_t == 1.0f) {
                v0 = 1.0f;
                float aw = anchors[a * 2 + 0], ah = anchors[a * 2 + 1];
                float sx = sigmoidf(p0);
                float sy = sigmoidf(p1);
                float pw = expf(p2) * aw;
                float ph = expf(p3) * ah;
                float giou = giou_fn(sx, sy, pw, ph, tx, ty, tw, th);
                v3 = bce_logits(x, fmaxf(giou, 0.0f));
                v4 = bce_logits(sx, tx) + bce_logits(sy, ty);
                float twl = logf(1e-16f + tw / aw);
                float thl = logf(1e-16f + th / ah);
                float dw = p2 - twl, dh = p3 - thl;
                v5 = dw * dw + dh * dh;
                v6 = 1.0f - giou;

                // 80-way log-softmax NLL, serial per obj thread (few of them)
                float mx = -1e30f;
                #pragma unroll 8
                for (int c = 0; c < NC_; ++c) mx = fmaxf(mx, p[5 + c]);
                float se = 0.0f;
                #pragma unroll 8
                for (int c = 0; c < NC_; ++c) se += expf(p[5 + c] - mx);
                int label = (int)t5;
                v7 = (mx + logf(se)) - p[5 + label];
            }
        }

        #pragma unroll
        for (int o = 32; o > 0; o >>= 1) {
            v0 += __shfl_xor(v0, o, 64);  v1 += __shfl_xor(v1, o, 64);
            v2 += __shfl_xor(v2, o, 64);  v3 += __shfl_xor(v3, o, 64);
            v4 += __shfl_xor(v4, o, 64);  v5 += __shfl_xor(v5, o, 64);
            v6 += __shfl_xor(v6, o, 64);  v7 += __shfl_xor(v7, o, 64);
        }
        if ((tid & 63) == 0) {
            int w = tid >> 6;
            s_w[w][0] = v0; s_w[w][1] = v1; s_w[w][2] = v2; s_w[w][3] = v3;
            s_w[w][4] = v4; s_w[w][5] = v5; s_w[w][6] = v6; s_w[w][7] = v7;
        }
        __syncthreads();
        if (tid < 8) {
            partials[b * PROW + tid] =
                s_w[0][tid] + s_w[1][tid] + s_w[2][tid] + s_w[3][tid];
        }
        if (tid == 0) {
            partials[b * PROW + 8] = 0.0f;   // no seg work in phase-1 blocks
            partials[b * PROW + 9] = 0.0f;
        }
    } else {
        // ==================== Phase 2: segmentation BCE ====================
        const int gw = (b - P1_BLOCKS) * 4 + wav;    // global wave id, 0..991

        // ---- Round 1: probe t-rows (lanes 0..2) + coeff prefetch (all) ----
        int   pc   = gw + lane * P2_WAVES;
        bool  in   = (lane < P2_K) && (pc < NCELL);
        float conf = 0.0f;
        int   lox = 0, loy = 0, ncols = 0, nrows = 0, idc = 0, parea = 0;
        if (in) {
            const float* t = target + (size_t)pc * 7;
            float t0 = t[0], t1 = t[1], t2 = t[2], t3 = t[3];
            conf = t[4];
            float t6 = t[6];
            region_bounds_v(t0, t1, t2, t3, (pc / S_) % S_, pc % S_,
                            lox, loy, ncols, nrows);
            parea = nrows * ncols;
            idc   = min(max((int)t6, 0), G_ - 1);
        }
        // coeff prefetch: static addresses, issues concurrently with probe.
        // halves hold cand 0 (lanes 0..31) / cand 1 (lanes 32..63);
        // cand 2 (if in range) on lanes 0..31 in a second register.
        const int m    = lane & 31;
        const int cA   = gw + (lane >> 5) * P2_WAVES;       // cand 0 or 1
        float cf01 = tanhf(preds[(size_t)cA * CH_ + 5 + NC_ + m]);
        const int c2   = gw + 2 * P2_WAVES;
        float cf2  = 0.0f;
        if (c2 < NCELL && lane < 32)
            cf2 = tanhf(preds[(size_t)c2 * CH_ + 5 + NC_ + m]);

        unsigned long long vmask = __ballot(in && conf == 1.0f && parea > 0);
        const int wave_nv = (int)__popcll(vmask);

        float wave_seg = 0.0f;   // only lane 0's copy matters
        while (vmask) {
            const int l = __ffsll(vmask) - 1;       // 0..2
            vmask &= vmask - 1;
            const int cell = gw + l * P2_WAVES;

            // broadcast probe results from lane l (register-only)
            const int rlox = __builtin_amdgcn_readlane(lox,   l);
            const int rloy = __builtin_amdgcn_readlane(loy,   l);
            const int rnc  = __builtin_amdgcn_readlane(ncols, l);
            const int rnr  = __builtin_amdgcn_readlane(nrows, l);
            const int rid  = __builtin_amdgcn_readlane(idc,   l);
            const int rn   = cell / (A_ * S_ * S_);
            const int area = rnr * rnc;

            // broadcast prefetched coefficients (register-only)
            const float src  = (l == 2) ? cf2 : cf01;
            const int   base = (l == 1) ? 32 : 0;
            float cm[NM_];
            #pragma unroll
            for (int mm = 0; mm < NM_; ++mm)
                cm[mm] = readlane_f(src, base + mm);

            const float* tm = masks  + ((size_t)(rn * G_ + rid)) * HW_;
            const float* pr = protos + (size_t)rn * NM_ * HW_;

            float lsum = 0.0f;
            for (int px = lane; px < area; px += 64) {
                int h = rloy + px / rnc;
                int w = rlox + px % rnc;
                int off = h * W_ + w;
                float inst = 0.0f;
                #pragma unroll
                for (int mm = 0; mm < NM_; ++mm)
                    inst += cm[mm] * pr[mm * HW_ + off];
                lsum += bce_logits(inst, tm[off]);
            }

            #pragma unroll
            for (int o = 32; o > 0; o >>= 1) lsum += __shfl_xor(lsum, o, 64);
            if (lane == 0) wave_seg += lsum / (float)area;
        }

        if (lane == 0) { s_seg[wav] = wave_seg; s_nv[wav] = wave_nv; }
        __syncthreads();
        if (tid == 0) {
            partials[b * PROW + 8] = s_seg[0] + s_seg[1] + s_seg[2] + s_seg[3];
            partials[b * PROW + 9] =
                (float)(s_nv[0] + s_nv[1] + s_nv[2] + s_nv[3]);
        }
    }

    // ================== Epilogue: last-block finalize ======================
    __syncthreads();            // drain ALL of this block's stores to L2
    if (tid == 0) {
        __threadfence();        // release: single per-block L2 writeback
        unsigned int old = atomicInc(ticket, MAIN_BLOCKS - 1u); // wraps at 255
        s_last = (old == MAIN_BLOCKS - 2u) ? 1 : 0;             // 256th arriver
    }
    __syncthreads();
    if (!s_last) return;

    if (tid < 64) {
        __threadfence();        // acquire: one invalidate in the reading wave
        const int t = tid;
        float s0 = 0.f, s1 = 0.f, s2 = 0.f, s3 = 0.f,
              s4 = 0.f, s5 = 0.f, s6 = 0.f, s7 = 0.f, s8 = 0.f, s9 = 0.f;
        if (t < 8) {
            s0 = partials[t * PROW + 0]; s1 = partials[t * PROW + 1];
            s2 = partials[t * PROW + 2]; s3 = partials[t * PROW + 3];
            s4 = partials[t * PROW + 4]; s5 = partials[t * PROW + 5];
            s6 = partials[t * PROW + 6]; s7 = partials[t * PROW + 7];
        }
        // slots 8/9: all 256 rows, 4 rows per thread
        #pragma unroll
        for (int r = t; r < MAIN_BLOCKS; r += 64) {
            s8 += partials[r * PROW + 8];
            s9 += partials[r * PROW + 9];
        }

        #pragma unroll
        for (int o = 32; o > 0; o >>= 1) {
            s0 += __shfl_xor(s0, o, 64);  s1 += __shfl_xor(s1, o, 64);
            s2 += __shfl_xor(s2, o, 64);  s3 += __shfl_xor(s3, o, 64);
            s4 += __shfl_xor(s4, o, 64);  s5 += __shfl_xor(s5, o, 64);
            s6 += __shfl_xor(s6, o, 64);  s7 += __shfl_xor(s7, o, 64);
            s8 += __shfl_xor(s8, o, 64);  s9 += __shfl_xor(s9, o, 64);
        }

        if (t == 0) {
            float n_obj   = s0;
            float n_noobj = s1;
            float noobj_loss = s2 / n_noobj;
            float obj_loss   = s3 / n_obj;
            float xy_bce     = s4 / (n_obj * 2.0f);
            float wh_mse     = s5 / (n_obj * 2.0f);
            float box_loss   = xy_bce + wh_mse + s6 / n_obj;
            float class_loss = s7 / n_obj;
            float seg_loss   = s8 / (s9 + 1e-9f);
            float box_l   = 8.0f * box_loss;
            float obj_l   = 2.0f * obj_loss;
            float noobj_l = 4.0f * noobj_loss;
            float cls_l   = 1.0f * class_loss;
            float seg_l   = 10.0f * seg_loss;
            out[0] = box_l;
            out[1] = obj_l;
            out[2] = noobj_l;
            out[3] = cls_l;
            out[4] = seg_l;
            out[5] = box_l + obj_l + noobj_l + cls_l + seg_l;
        }
    }
}

extern "C" void kernel_launch(void* const* d_in, const int* in_sizes, int n_in,
                              void* d_out, int out_size, void* d_ws, size_t ws_size,
                              hipStream_t stream) {
    const float* preds   = (const float*)d_in[0];
    const float* target  = (const float*)d_in[1];
    const float* anchors = (const float*)d_in[2];
    const float* protos  = (const float*)d_in[3];
    const float* masks   = (const float*)d_in[4];
    // d_in[5] = num_classes (80), d_in[6] = num_masks (32) — hard-coded.

    float* partials      = (float*)d_ws;
    unsigned int* ticket = (unsigned int*)(partials + MAIN_BLOCKS * PROW);
    float* out           = (float*)d_out;

    yolo_fused_kernel<<<MAIN_BLOCKS, 256, 0, stream>>>(preds, target, anchors,
                                                       protos, masks, partials,
                                                       ticket, out);
}

// Round 5
// 93.323 us; speedup vs baseline: 1.0220x; 1.0220x over previous
//
#include <hip/hip_runtime.h>
#include <math.h>

// Problem constants (fixed by setup_inputs in the reference)
#define N_  4
#define A_  3
#define S_  13
#define NC_ 80
#define NM_ 32
#define G_  16
#define H_  104
#define W_  104
#define CH_ (5 + NC_ + NM_)   // 117
#define HW_ (H_ * W_)
#define NCELL (N_ * A_ * S_ * S_)  // 2028

#define MAIN_BLOCKS 64
#define PROW 16     // floats per partial row (16*4 = 64B; rows padded)
#define P2_WAVES ((MAIN_BLOCKS - 8) * 4)   // 224 phase-2 waves (blocks 8..63)
#define P2_K 10     // candidates per wave: ceil(2028/224) = 10 (lanes 0..9)

// d_ws layout: partials[MAIN_BLOCKS][PROW] floats, then one u32 ticket.
// slots 0..7 (valid only rows 0..7): n_obj, n_noobj, noobj_bce, obj_bce,
//                                    xy_bce, wh_mse, one_minus_giou, nll
// slots 8..9 (all rows): seg_sum, n_valid  (rows 0..7 write zeros)
// All written UNCONDITIONALLY by their owning block -> no memset needed.
//
// Ticket correctness under 0xAA poison: atomicInc(ticket, 63) stores
// (old >= 63 ? 0 : old+1). Start state is either 0xAAAAAAAA (poison) or 63
// (our leftover from a prior iteration); both are >= 63, so arrival 1 wraps
// to 0 and arrivals 2..64 observe old = 0..62. The 64th arriver ALWAYS
// observes old == 62 and runs finalize; end state is always 63.
//
// Fence discipline (R1 lesson, R3-validated): __syncthreads() drains the
// block's stores to L2, then ONE tid-0 __threadfence() (release) before the
// ticket bump, and ONE acquire fence in the reading wave of the last block.
// Per-thread fences in all blocks cost µs (R1: +3.2 µs). R4 lesson: keep 64
// blocks / 224 probing waves — more waves with unconditional prefetch, wider
// ticket fan-in, and a 256-row finalize sweep cost ~+2 µs net.

__device__ __forceinline__ float bce_logits(float x, float z) {
    return fmaxf(x, 0.0f) - x * z + log1pf(expf(-fabsf(x)));
}

__device__ __forceinline__ float sigmoidf(float x) {
    return 1.0f / (1.0f + expf(-x));
}

__device__ __forceinline__ float readlane_f(float v, int l) {
    return __int_as_float(__builtin_amdgcn_readlane(__float_as_int(v), l));
}

__device__ __forceinline__ float giou_fn(float cx1, float cy1, float w1, float h1,
                                         float cx2, float cy2, float w2, float h2) {
    const float eps = 1e-9f;
    float b1x1 = cx1 - w1 * 0.5f, b1y1 = cy1 - h1 * 0.5f;
    float b1x2 = cx1 + w1 * 0.5f, b1y2 = cy1 + h1 * 0.5f;
    float b2x1 = cx2 - w2 * 0.5f, b2y1 = cy2 - h2 * 0.5f;
    float b2x2 = cx2 + w2 * 0.5f, b2y2 = cy2 + h2 * 0.5f;
    float a1 = fmaxf(b1x2 - b1x1, 0.0f) * fmaxf(b1y2 - b1y1, 0.0f) + eps;
    float a2 = fmaxf(b2x2 - b2x1, 0.0f) * fmaxf(b2y2 - b2y1, 0.0f) + eps;
    float iw = fmaxf(fminf(b1x2, b2x2) - fmaxf(b1x1, b2x1), 0.0f);
    float ih = fmaxf(fminf(b1y2, b2y2) - fmaxf(b1y1, b2y1), 0.0f);
    float inter = iw * ih + eps;
    float uni   = a1 + a2 - inter + eps;
    float iou   = inter / uni;
    float cw = fmaxf(b1x2, b2x2) - fminf(b1x1, b2x1);
    float ch = fmaxf(b1y2, b2y2) - fminf(b1y1, b2y1);
    float carea = cw * ch + eps;
    return iou - (carea - uni) / carea;
}

// box pixel bounds for a cell (value form)
__device__ __forceinline__ void region_bounds_v(float t0, float t1, float t2, float t3,
                                                int i, int j,
                                                int& lox, int& loy, int& ncols, int& nrows) {
    float bx = (t0 + (float)j) * ((float)W_ / (float)S_);
    float by = (t1 + (float)i) * ((float)H_ / (float)S_);
    float bw = t2 * ((float)W_ / (float)S_);
    float bh = t3 * ((float)H_ / (float)S_);
    int x1 = (int)floorf(bx - bw * 0.5f);
    int x2 = (int)floorf(bx + bw * 0.5f);
    int y1 = (int)floorf(by - bh * 0.5f);
    int y2 = (int)floorf(by + bh * 0.5f);
    lox = max(x1, 0); loy = max(y1, 0);
    ncols = max(min(x2, W_) - lox, 0);
    nrows = max(min(y2, H_) - loy, 0);
}

// ---------------------------------------------------------------------------
// SINGLE fused kernel, 64 blocks x 256 threads (R3 configuration, best
// measured 92.84 µs):
//  Blocks 0..7  : phase 1 — thread-per-cell scalar losses -> partial rows.
//  Blocks 8..63 : phase 2 — seg BCE, global wave-per-cell (224 waves).
//    Probe: lanes 0..9 load the FULL t-row for candidates c = gw + 224*k and
//    compute bounds in-register -> ballot. Per valid cell: bounds/id come
//    from readlane (no t re-read); coeff + proto + mask loads issue in one
//    round. Serial cold-miss depth: 2 rounds (probe, then coeff||proto).
//  Epilogue: per-block single-thread release fence + ticket; 64th arriver
//    acquires and reduces all 64 partial rows, writes the 6 outputs.
// ---------------------------------------------------------------------------
__global__ __launch_bounds__(256) void yolo_fused_kernel(
    const float* __restrict__ preds,    // (N,A,S,S,117)
    const float* __restrict__ target,   // (N,A,S,S,7)
    const float* __restrict__ anchors,  // (A,2)
    const float* __restrict__ protos,   // (N,32,H,W)
    const float* __restrict__ masks,    // (N,16,H,W)
    float* __restrict__ partials,
    unsigned int* __restrict__ ticket,
    float* __restrict__ out)
{
    const int b    = blockIdx.x;
    const int tid  = threadIdx.x;
    const int wav  = tid >> 6;
    const int lane = tid & 63;

    __shared__ float s_w[4][8];     // phase-1 cross-wave
    __shared__ float s_seg[4];      // phase-2 cross-wave
    __shared__ int   s_nv[4];
    __shared__ int   s_last;

    if (b < 8) {
        // ===================== Phase 1: scalar losses ======================
        const int cell = b * 256 + tid;
        float v0 = 0.f, v1 = 0.f, v2 = 0.f, v3 = 0.f,
              v4 = 0.f, v5 = 0.f, v6 = 0.f, v7 = 0.f;

        if (cell < NCELL) {
            const int a = (cell / (S_ * S_)) % A_;
            const float* t = target + (size_t)cell * 7;
            const float* p = preds  + (size_t)cell * CH_;
            const float conf_t = t[4];
            const float x = p[4];

            if (conf_t == 0.0f) {
                v1 = 1.0f;
                v2 = bce_logits(x, 0.0f);
            } else if (conf_t == 1.0f) {
                v0 = 1.0f;
                float tx = t[0], ty = t[1], tw = t[2], th = t[3];
                float aw = anchors[a * 2 + 0], ah = anchors[a * 2 + 1];
                float sx = sigmoidf(p[0]);
                float sy = sigmoidf(p[1]);
                float pw = expf(p[2]) * aw;
                float ph = expf(p[3]) * ah;
                float giou = giou_fn(sx, sy, pw, ph, tx, ty, tw, th);
                v3 = bce_logits(x, fmaxf(giou, 0.0f));
                v4 = bce_logits(sx, tx) + bce_logits(sy, ty);
                float twl = logf(1e-16f + tw / aw);
                float thl = logf(1e-16f + th / ah);
                float dw = p[2] - twl, dh = p[3] - thl;
                v5 = dw * dw + dh * dh;
                v6 = 1.0f - giou;

                // 80-way log-softmax NLL, serial per obj thread (few of them)
                float mx = -1e30f;
                #pragma unroll 8
                for (int c = 0; c < NC_; ++c) mx = fmaxf(mx, p[5 + c]);
                float se = 0.0f;
                #pragma unroll 8
                for (int c = 0; c < NC_; ++c) se += expf(p[5 + c] - mx);
                int label = (int)t[5];
                v7 = (mx + logf(se)) - p[5 + label];
            }
        }

        #pragma unroll
        for (int o = 32; o > 0; o >>= 1) {
            v0 += __shfl_xor(v0, o, 64);  v1 += __shfl_xor(v1, o, 64);
            v2 += __shfl_xor(v2, o, 64);  v3 += __shfl_xor(v3, o, 64);
            v4 += __shfl_xor(v4, o, 64);  v5 += __shfl_xor(v5, o, 64);
            v6 += __shfl_xor(v6, o, 64);  v7 += __shfl_xor(v7, o, 64);
        }
        if ((tid & 63) == 0) {
            int w = tid >> 6;
            s_w[w][0] = v0; s_w[w][1] = v1; s_w[w][2] = v2; s_w[w][3] = v3;
            s_w[w][4] = v4; s_w[w][5] = v5; s_w[w][6] = v6; s_w[w][7] = v7;
        }
        __syncthreads();
        if (tid < 8) {
            partials[b * PROW + tid] =
                s_w[0][tid] + s_w[1][tid] + s_w[2][tid] + s_w[3][tid];
        }
        if (tid == 0) {
            partials[b * PROW + 8] = 0.0f;   // no seg work in phase-1 blocks
            partials[b * PROW + 9] = 0.0f;
        }
    } else {
        // ==================== Phase 2: segmentation BCE ====================
        const int gw = (b - 8) * 4 + wav;        // global wave id, 0..223

        // Probe: lanes 0..9 own candidates c = gw + 224*k. Load the FULL
        // t-row and compute bounds in-register (one cold round).
        int   pc   = gw + lane * P2_WAVES;
        bool  in   = (lane < P2_K) && (pc < NCELL);
        float conf = 0.0f;
        int   lox = 0, loy = 0, ncols = 0, nrows = 0, idc = 0, parea = 0;
        if (in) {
            const float* t = target + (size_t)pc * 7;
            float t0 = t[0], t1 = t[1], t2 = t[2], t3 = t[3];
            conf = t[4];
            float t6 = t[6];
            region_bounds_v(t0, t1, t2, t3, (pc / S_) % S_, pc % S_,
                            lox, loy, ncols, nrows);
            parea = nrows * ncols;
            idc   = min(max((int)t6, 0), G_ - 1);
        }
        unsigned long long vmask = __ballot(in && conf == 1.0f && parea > 0);
        const int wave_nv = (int)__popcll(vmask);

        float wave_seg = 0.0f;   // only lane 0's copy matters
        while (vmask) {
            const int l = __ffsll(vmask) - 1;
            vmask &= vmask - 1;
            const int cell = gw + l * P2_WAVES;

            // broadcast probe results from lane l (register-only, no memory)
            const int rlox = __builtin_amdgcn_readlane(lox,   l);
            const int rloy = __builtin_amdgcn_readlane(loy,   l);
            const int rnc  = __builtin_amdgcn_readlane(ncols, l);
            const int rnr  = __builtin_amdgcn_readlane(nrows, l);
            const int rid  = __builtin_amdgcn_readlane(idc,   l);
            const int rn   = cell / (A_ * S_ * S_);
            const int area = rnr * rnc;

            const float* p  = preds  + (size_t)cell * CH_;
            const float* tm = masks  + ((size_t)(rn * G_ + rid)) * HW_;
            const float* pr = protos + (size_t)rn * NM_ * HW_;

            // lanes 0..31 load+tanh coefficients; proto/mask loads below are
            // independent of them, so they overlap the coeff miss.
            float cv = 0.0f;
            if (lane < NM_) cv = tanhf(p[5 + NC_ + lane]);
            float cm[NM_];
            #pragma unroll
            for (int m = 0; m < NM_; ++m) cm[m] = readlane_f(cv, m);

            float lsum = 0.0f;
            for (int px = lane; px < area; px += 64) {
                int h = rloy + px / rnc;
                int w = rlox + px % rnc;
                int off = h * W_ + w;
                float inst = 0.0f;
                #pragma unroll
                for (int m = 0; m < NM_; ++m)
                    inst += cm[m] * pr[m * HW_ + off];
                lsum += bce_logits(inst, tm[off]);
            }

            #pragma unroll
            for (int o = 32; o > 0; o >>= 1) lsum += __shfl_xor(lsum, o, 64);
            if (lane == 0) wave_seg += lsum / (float)area;
        }

        if (lane == 0) { s_seg[wav] = wave_seg; s_nv[wav] = wave_nv; }
        __syncthreads();
        if (tid == 0) {
            partials[b * PROW + 8] = s_seg[0] + s_seg[1] + s_seg[2] + s_seg[3];
            partials[b * PROW + 9] =
                (float)(s_nv[0] + s_nv[1] + s_nv[2] + s_nv[3]);
        }
    }

    // ================== Epilogue: last-block finalize ======================
    __syncthreads();            // drain ALL of this block's stores to L2
    if (tid == 0) {
        __threadfence();        // release: single per-block L2 writeback
        unsigned int old = atomicInc(ticket, MAIN_BLOCKS - 1u); // wraps at 63
        s_last = (old == MAIN_BLOCKS - 2u) ? 1 : 0;             // 64th arriver
    }
    __syncthreads();
    if (!s_last) return;

    if (tid < 64) {
        __threadfence();        // acquire: one invalidate in the reading wave
        const int t = tid;
        float s0 = 0.f, s1 = 0.f, s2 = 0.f, s3 = 0.f,
              s4 = 0.f, s5 = 0.f, s6 = 0.f, s7 = 0.f, s8 = 0.f, s9 = 0.f;
        if (t < 8) {
            s0 = partials[t * PROW + 0]; s1 = partials[t * PROW + 1];
            s2 = partials[t * PROW + 2]; s3 = partials[t * PROW + 3];
            s4 = partials[t * PROW + 4]; s5 = partials[t * PROW + 5];
            s6 = partials[t * PROW + 6]; s7 = partials[t * PROW + 7];
        }
        s8 = partials[t * PROW + 8];
        s9 = partials[t * PROW + 9];

        #pragma unroll
        for (int o = 32; o > 0; o >>= 1) {
            s0 += __shfl_xor(s0, o, 64);  s1 += __shfl_xor(s1, o, 64);
            s2 += __shfl_xor(s2, o, 64);  s3 += __shfl_xor(s3, o, 64);
            s4 += __shfl_xor(s4, o, 64);  s5 += __shfl_xor(s5, o, 64);
            s6 += __shfl_xor(s6, o, 64);  s7 += __shfl_xor(s7, o, 64);
            s8 += __shfl_xor(s8, o, 64);  s9 += __shfl_xor(s9, o, 64);
        }

        if (t == 0) {
            float n_obj   = s0;
            float n_noobj = s1;
            float noobj_loss = s2 / n_noobj;
            float obj_loss   = s3 / n_obj;
            float xy_bce     = s4 / (n_obj * 2.0f);
            float wh_mse     = s5 / (n_obj * 2.0f);
            float box_loss   = xy_bce + wh_mse + s6 / n_obj;
            float class_loss = s7 / n_obj;
            float seg_loss   = s8 / (s9 + 1e-9f);
            float box_l   = 8.0f * box_loss;
            float obj_l   = 2.0f * obj_loss;
            float noobj_l = 4.0f * noobj_loss;
            float cls_l   = 1.0f * class_loss;
            float seg_l   = 10.0f * seg_loss;
            out[0] = box_l;
            out[1] = obj_l;
            out[2] = noobj_l;
            out[3] = cls_l;
            out[4] = seg_l;
            out[5] = box_l + obj_l + noobj_l + cls_l + seg_l;
        }
    }
}

extern "C" void kernel_launch(void* const* d_in, const int* in_sizes, int n_in,
                              void* d_out, int out_size, void* d_ws, size_t ws_size,
                              hipStream_t stream) {
    const float* preds   = (const float*)d_in[0];
    const float* target  = (const float*)d_in[1];
    const float* anchors = (const float*)d_in[2];
    const float* protos  = (const float*)d_in[3];
    const float* masks   = (const float*)d_in[4];
    // d_in[5] = num_classes (80), d_in[6] = num_masks (32) — hard-coded.

    float* partials      = (float*)d_ws;
    unsigned int* ticket = (unsigned int*)(partials + MAIN_BLOCKS * PROW);
    float* out           = (float*)d_out;

    yolo_fused_kernel<<<MAIN_BLOCKS, 256, 0, stream>>>(preds, target, anchors,
                                                       protos, masks, partials,
                                                       ticket, out);
}